// Round 1
// baseline (286.084 us; speedup 1.0000x reference)
//
#include <hip/hip_runtime.h>
#include <hip/hip_bf16.h>
#include <stdint.h>

#define BM 128
#define BN 128
#define BK 32

typedef __attribute__((ext_vector_type(8))) short bf16x8;
typedef __attribute__((ext_vector_type(4))) float floatx4;

// ---- helpers ------------------------------------------------------------

__device__ __forceinline__ unsigned short f2bf(float f) {
    unsigned int x;
    __builtin_memcpy(&x, &f, 4);
    unsigned int r = (x + 0x7fffu + ((x >> 16) & 1u)) >> 16;  // RNE
    return (unsigned short)r;
}

__device__ __forceinline__ float bf2f(unsigned short u) {
    unsigned int x = ((unsigned int)u) << 16;
    float f;
    __builtin_memcpy(&f, &x, 4);
    return f;
}

// async global->LDS, 16B per lane.  LDS dest must be wave-uniform base + lane*16.
__device__ __forceinline__ void async_copy16(const void* g, void* l) {
    __builtin_amdgcn_global_load_lds(
        (const __attribute__((address_space(1))) void*)(uintptr_t)g,
        (__attribute__((address_space(3))) void*)(uint32_t)(uintptr_t)l,
        16, 0, 0);
}

// ---- kernel 1: fp32 -> bf16 convert (x) ---------------------------------

__global__ void cvt_f32_to_bf16(const float* __restrict__ in,
                                unsigned short* __restrict__ out, int n4) {
    int i = blockIdx.x * 256 + threadIdx.x;
    if (i >= n4) return;
    float4 v = ((const float4*)in)[i];
    ushort4 o;
    o.x = f2bf(v.x);
    o.y = f2bf(v.y);
    o.z = f2bf(v.z);
    o.w = f2bf(v.w);
    ((ushort4*)out)[i] = o;
}

// ---- kernel 2: W [1024,1024] fp32 -> W^T bf16, 3 matrices ---------------

__global__ void transpose_w(const float* __restrict__ Wq,
                            const float* __restrict__ Wk,
                            const float* __restrict__ Wv,
                            unsigned short* __restrict__ wT) {
    __shared__ float tile[32][33];
    const float* W = blockIdx.z == 0 ? Wq : (blockIdx.z == 1 ? Wk : Wv);
    int bx = blockIdx.x * 32;  // input col (n)
    int by = blockIdx.y * 32;  // input row (k)
    int tx = threadIdx.x, ty = threadIdx.y;  // 32x8
    for (int r = 0; r < 32; r += 8)
        tile[ty + r][tx] = W[(size_t)(by + ty + r) * 1024 + bx + tx];
    __syncthreads();
    unsigned short* o = wT + (size_t)blockIdx.z * 1024 * 1024;
    for (int r = 0; r < 32; r += 8)
        o[(size_t)(bx + ty + r) * 1024 + by + tx] = f2bf(tile[tx][ty + r]);
}

// ---- kernel 3: V slice of qkv -> V^T per batch --------------------------

__global__ void transpose_v(const unsigned short* __restrict__ qkv,
                            unsigned short* __restrict__ vt) {
    __shared__ unsigned short tile[32][34];
    int b = blockIdx.z;
    int j0 = blockIdx.x * 32;  // seq
    int d0 = blockIdx.y * 32;  // dim
    int tx = threadIdx.x, ty = threadIdx.y;  // 32x8
    for (int r = 0; r < 32; r += 8)
        tile[ty + r][tx] = qkv[(size_t)(b * 2048 + j0 + ty + r) * 3072 + 2048 + d0 + tx];
    __syncthreads();
    unsigned short* o = vt + (size_t)b * 1024 * 2048;
    for (int r = 0; r < 32; r += 8)
        o[(size_t)(d0 + ty + r) * 2048 + j0 + tx] = tile[tx][ty + r];
}

// ---- the GEMM: C[m][n] = scale * sum_k A[m][k] * Bt[n][k] ---------------
// m97-style: 128x128 tile, BK=32, 4 waves (2x2), 4x4 16x16x32 bf16 MFMA/wave,
// global_load_lds width-16 staging into unpadded LDS (layout = lane order).

template <bool OUT_BF16, bool CAUSAL_SKIP, bool K_LIMIT>
__global__ __launch_bounds__(256, 2) void gemm_bt(
    const unsigned short* __restrict__ A, int lda, long long sAb,
    const unsigned short* __restrict__ B, int ldb, long long sBb,
    void* __restrict__ C, int ldc, long long sCb, int K, float scale) {
    int n0 = blockIdx.x * BN;
    int m0 = blockIdx.y * BM;
    if (CAUSAL_SKIP && n0 > m0 + (BM - 1)) return;  // tile fully above diagonal
    int kend = K;
    if (K_LIMIT) {  // causal PV: P[i][j]==0 for j>i, so stop at row-block end
        int lim = m0 + BM;
        kend = lim < K ? lim : K;
    }
    const unsigned short* Ab = A + (size_t)blockIdx.z * sAb;
    const unsigned short* Bb = B + (size_t)blockIdx.z * sBb;

    __shared__ __align__(16) unsigned short As[BM * BK];  // 8 KB
    __shared__ __align__(16) unsigned short Bs[BN * BK];  // 8 KB

    int tid = threadIdx.x;
    int lane = tid & 63;
    int wave = tid >> 6;
    int wm = (wave >> 1) * 64;
    int wn = (wave & 1) * 64;
    int fr = lane & 15;  // fragment row (m) / col (n)
    int kq = lane >> 4;  // k-quad: frag k-offset = kq*8

    floatx4 acc[4][4] = {};

    // staging: chunk c (16B = 8 bf16) covers tile row c>>2, k-offset (c&3)*8.
    // thread t handles chunks t and t+256; LDS offset = c*16B = wave-uniform
    // base + lane*16 (global_load_lds requirement).
    int c0 = tid, c1 = tid + 256;
    int ar0 = c0 >> 2, ak0 = (c0 & 3) * 8;
    int ar1 = c1 >> 2, ak1 = (c1 & 3) * 8;

    for (int k0 = 0; k0 < kend; k0 += BK) {
        async_copy16(Ab + (size_t)(m0 + ar0) * lda + k0 + ak0, &As[c0 * 8]);
        async_copy16(Ab + (size_t)(m0 + ar1) * lda + k0 + ak1, &As[c1 * 8]);
        async_copy16(Bb + (size_t)(n0 + ar0) * ldb + k0 + ak0, &Bs[c0 * 8]);
        async_copy16(Bb + (size_t)(n0 + ar1) * ldb + k0 + ak1, &Bs[c1 * 8]);
        __syncthreads();  // drains vmcnt before LDS reads

        bf16x8 af[4], bfg[4];
#pragma unroll
        for (int mi = 0; mi < 4; mi++)
            af[mi] = *(const bf16x8*)&As[(wm + mi * 16 + fr) * BK + kq * 8];
#pragma unroll
        for (int ni = 0; ni < 4; ni++)
            bfg[ni] = *(const bf16x8*)&Bs[(wn + ni * 16 + fr) * BK + kq * 8];
#pragma unroll
        for (int mi = 0; mi < 4; mi++)
#pragma unroll
            for (int ni = 0; ni < 4; ni++)
                acc[mi][ni] = __builtin_amdgcn_mfma_f32_16x16x32_bf16(
                    af[mi], bfg[ni], acc[mi][ni], 0, 0, 0);
        __syncthreads();  // protect LDS before next stage
    }

    // epilogue: C/D layout col=lane&15, row=(lane>>4)*4+reg  (m89/m91-verified)
    int col0 = n0 + wn + fr;
    int rbase = m0 + wm + kq * 4;
    if (OUT_BF16) {
        unsigned short* Cb = (unsigned short*)C + (size_t)blockIdx.z * sCb;
#pragma unroll
        for (int mi = 0; mi < 4; mi++)
#pragma unroll
            for (int ni = 0; ni < 4; ni++)
#pragma unroll
                for (int r = 0; r < 4; r++)
                    Cb[(size_t)(rbase + mi * 16 + r) * ldc + col0 + ni * 16] =
                        f2bf(acc[mi][ni][r] * scale);
    } else {
        float* Cb = (float*)C + (size_t)blockIdx.z * sCb;
#pragma unroll
        for (int mi = 0; mi < 4; mi++)
#pragma unroll
            for (int ni = 0; ni < 4; ni++)
#pragma unroll
                for (int r = 0; r < 4; r++)
                    Cb[(size_t)(rbase + mi * 16 + r) * ldc + col0 + ni * 16] =
                        acc[mi][ni][r] * scale;
    }
}

// ---- kernel: causal row softmax, in place on bf16 S ---------------------

__global__ void softmax_causal(unsigned short* __restrict__ S) {
    int row = blockIdx.x;  // b*2048 + i
    int i = row & 2047;
    unsigned short* s = S + (size_t)row * 2048;
    int len = i + 1;
    __shared__ float red[256];
    int t = threadIdx.x;

    float m = -3.0e38f;
    for (int j = t; j < len; j += 256) m = fmaxf(m, bf2f(s[j]));
    red[t] = m;
    __syncthreads();
    for (int o = 128; o > 0; o >>= 1) {
        if (t < o) red[t] = fmaxf(red[t], red[t + o]);
        __syncthreads();
    }
    m = red[0];
    __syncthreads();

    float sum = 0.f;
    for (int j = t; j < len; j += 256) sum += __expf(bf2f(s[j]) - m);
    red[t] = sum;
    __syncthreads();
    for (int o = 128; o > 0; o >>= 1) {
        if (t < o) red[t] += red[t + o];
        __syncthreads();
    }
    float inv = 1.0f / red[0];

    for (int j = t; j < len; j += 256)
        s[j] = f2bf(__expf(bf2f(s[j]) - m) * inv);
    for (int j = len + t; j < 2048; j += 256) s[j] = 0;  // zero masked tail
}

// ---- launch -------------------------------------------------------------

extern "C" void kernel_launch(void* const* d_in, const int* in_sizes, int n_in,
                              void* d_out, int out_size, void* d_ws,
                              size_t ws_size, hipStream_t stream) {
    const float* x = (const float*)d_in[0];
    const float* Wq = (const float*)d_in[1];
    const float* Wk = (const float*)d_in[2];
    const float* Wv = (const float*)d_in[3];
    // causal_mask (d_in[4]) is always 1 in this problem — hardcoded causal.

    char* ws = (char*)d_ws;
    // layout (bytes):
    //   qkv [8192][3072] bf16 : 0        .. 50331648
    //   S   [4][2048][2048]   : 50331648 .. 83886080
    //   xb  [8192][1024]      : 83886080 .. 100663296   (dead after QKV gemm)
    //   vt  [4][1024][2048]   : 83886080  (aliases xb — written after xb dies)
    //   wT  [3072][1024]      : 100663296 .. 106954752
    unsigned short* qkv = (unsigned short*)(ws);
    unsigned short* S = (unsigned short*)(ws + 50331648);
    unsigned short* xb = (unsigned short*)(ws + 83886080);
    unsigned short* vt = (unsigned short*)(ws + 83886080);
    unsigned short* wT = (unsigned short*)(ws + 100663296);

    // 1. x -> bf16  (8388608 elems, 4/thread)
    cvt_f32_to_bf16<<<8192, 256, 0, stream>>>(x, xb, 8388608 / 4);
    // 2. W -> W^T bf16 (3 matrices)
    transpose_w<<<dim3(32, 32, 3), dim3(32, 8), 0, stream>>>(Wq, Wk, Wv, wT);
    // 3. qkv = xb @ [Wq|Wk|Wv]   (M=8192, N=3072, K=1024)
    gemm_bt<true, false, false><<<dim3(24, 64, 1), 256, 0, stream>>>(
        xb, 1024, 0LL, wT, 1024, 0LL, qkv, 3072, 0LL, 1024, 1.0f);
    // 4. V -> V^T per batch
    transpose_v<<<dim3(64, 32, 4), dim3(32, 8), 0, stream>>>(qkv, vt);
    // 5. S = scale * Q K^T  (per batch; skip tiles above diagonal)
    gemm_bt<true, true, false><<<dim3(16, 16, 4), 256, 0, stream>>>(
        qkv, 3072, 2048LL * 3072, qkv + 1024, 3072, 2048LL * 3072, S, 2048,
        2048LL * 2048, 1024, 0.03125f);
    // 6. causal softmax rows, in place (P in bf16)
    softmax_causal<<<8192, 256, 0, stream>>>(S);
    // 7. O = P @ V  (per batch, K limited to causal extent)
    gemm_bt<false, false, true><<<dim3(8, 16, 4), 256, 0, stream>>>(
        S, 2048, 2048LL * 2048, vt, 2048, 1024LL * 2048, d_out, 1024,
        2048LL * 1024, 2048, 1.0f);
}

// Round 2
// 281.037 us; speedup vs baseline: 1.0180x; 1.0180x over previous
//
#include <hip/hip_runtime.h>
#include <hip/hip_bf16.h>
#include <stdint.h>

#define BM 128
#define BN 128
#define BK 64

typedef __attribute__((ext_vector_type(8))) short bf16x8;
typedef __attribute__((ext_vector_type(4))) float floatx4;

// ---- helpers ------------------------------------------------------------

__device__ __forceinline__ unsigned short f2bf(float f) {
    unsigned int x;
    __builtin_memcpy(&x, &f, 4);
    unsigned int r = (x + 0x7fffu + ((x >> 16) & 1u)) >> 16;  // RNE
    return (unsigned short)r;
}

__device__ __forceinline__ float bf2f_hi(unsigned int u_hi_masked) {
    float f;
    __builtin_memcpy(&f, &u_hi_masked, 4);
    return f;
}

// async global->LDS, 16B per lane.  LDS dest must be wave-uniform base + lane*16.
__device__ __forceinline__ void async_copy16(const void* g, void* l) {
    __builtin_amdgcn_global_load_lds(
        (const __attribute__((address_space(1))) void*)(uintptr_t)g,
        (__attribute__((address_space(3))) void*)(uint32_t)(uintptr_t)l,
        16, 0, 0);
}

// ---- kernel 1: fp32 -> bf16 convert (x) ---------------------------------

__global__ void cvt_f32_to_bf16(const float* __restrict__ in,
                                unsigned short* __restrict__ out, int n4) {
    int i = blockIdx.x * 256 + threadIdx.x;
    if (i >= n4) return;
    float4 v = ((const float4*)in)[i];
    ushort4 o;
    o.x = f2bf(v.x);
    o.y = f2bf(v.y);
    o.z = f2bf(v.z);
    o.w = f2bf(v.w);
    ((ushort4*)out)[i] = o;
}

// ---- kernel 2: W [1024,1024] fp32 -> W^T bf16, 3 matrices ---------------

__global__ void transpose_w(const float* __restrict__ Wq,
                            const float* __restrict__ Wk,
                            const float* __restrict__ Wv,
                            unsigned short* __restrict__ wT) {
    __shared__ float tile[32][33];
    const float* W = blockIdx.z == 0 ? Wq : (blockIdx.z == 1 ? Wk : Wv);
    int bx = blockIdx.x * 32;  // input col (n)
    int by = blockIdx.y * 32;  // input row (k)
    int tx = threadIdx.x, ty = threadIdx.y;  // 32x8
    for (int r = 0; r < 32; r += 8)
        tile[ty + r][tx] = W[(size_t)(by + ty + r) * 1024 + bx + tx];
    __syncthreads();
    unsigned short* o = wT + (size_t)blockIdx.z * 1024 * 1024;
    for (int r = 0; r < 32; r += 8)
        o[(size_t)(bx + ty + r) * 1024 + by + tx] = f2bf(tile[tx][ty + r]);
}

// ---- kernel 3: V slice of qkv -> V^T per batch --------------------------

__global__ void transpose_v(const unsigned short* __restrict__ qkv,
                            unsigned short* __restrict__ vt) {
    __shared__ unsigned short tile[32][34];
    int b = blockIdx.z;
    int j0 = blockIdx.x * 32;  // seq
    int d0 = blockIdx.y * 32;  // dim
    int tx = threadIdx.x, ty = threadIdx.y;  // 32x8
    for (int r = 0; r < 32; r += 8)
        tile[ty + r][tx] = qkv[(size_t)(b * 2048 + j0 + ty + r) * 3072 + 2048 + d0 + tx];
    __syncthreads();
    unsigned short* o = vt + (size_t)b * 1024 * 2048;
    for (int r = 0; r < 32; r += 8)
        o[(size_t)(d0 + ty + r) * 2048 + j0 + tx] = tile[tx][ty + r];
}

// ---- the GEMM: C[m][n] = scale * sum_k A[m][k] * Bt[n][k] ---------------
// m97-style: 128x128 tile, BK=64 (half the barriers of BK=32), 4 waves (2x2),
// 2x 16 16x16x32 bf16 MFMA per k-iter, global_load_lds width-16 staging into
// unpadded row-major LDS [row][64] (layout = lane order, a hard requirement).

template <bool OUT_BF16, bool CAUSAL_SKIP, bool K_LIMIT>
__global__ __launch_bounds__(256, 2) void gemm_bt(
    const unsigned short* __restrict__ A, int lda, long long sAb,
    const unsigned short* __restrict__ B, int ldb, long long sBb,
    void* __restrict__ C, int ldc, long long sCb, int K, float scale) {
    int n0 = blockIdx.x * BN;
    int m0 = blockIdx.y * BM;
    if (CAUSAL_SKIP && n0 > m0 + (BM - 1)) return;  // tile fully above diagonal
    int kend = K;
    if (K_LIMIT) {  // causal PV: P[i][j]==0 for j>i, so stop at row-block end
        int lim = m0 + BM;
        kend = lim < K ? lim : K;
    }
    const unsigned short* Ab = A + (size_t)blockIdx.z * sAb;
    const unsigned short* Bb = B + (size_t)blockIdx.z * sBb;

    __shared__ __align__(16) unsigned short As[BM * BK];  // 16 KB
    __shared__ __align__(16) unsigned short Bs[BN * BK];  // 16 KB

    int tid = threadIdx.x;
    int lane = tid & 63;
    int wave = tid >> 6;
    int wm = (wave >> 1) * 64;
    int wn = (wave & 1) * 64;
    int fr = lane & 15;  // fragment row (m) / col (n)
    int kq = lane >> 4;  // k-quad: frag k-chunk base

    floatx4 acc[4][4] = {};

    for (int k0 = 0; k0 < kend; k0 += BK) {
        // staging: chunk c (16B = 8 bf16) covers row c>>3, k-offset (c&7)*8.
        // LDS offset = c*16B (contiguous in lane order: global_load_lds req).
#pragma unroll
        for (int q = 0; q < 4; q++) {
            int c = tid + q * 256;
            int r = c >> 3, ko = (c & 7) * 8;
            async_copy16(Ab + (size_t)(m0 + r) * lda + k0 + ko, &As[c * 8]);
            async_copy16(Bb + (size_t)(n0 + r) * ldb + k0 + ko, &Bs[c * 8]);
        }
        __syncthreads();  // drains vmcnt before LDS reads

#pragma unroll
        for (int kh = 0; kh < 2; kh++) {
            int kc = kh * 4 + kq;
            bf16x8 af[4], bfg[4];
#pragma unroll
            for (int mi = 0; mi < 4; mi++)
                af[mi] = *(const bf16x8*)&As[(wm + mi * 16 + fr) * BK + kc * 8];
#pragma unroll
            for (int ni = 0; ni < 4; ni++)
                bfg[ni] = *(const bf16x8*)&Bs[(wn + ni * 16 + fr) * BK + kc * 8];
#pragma unroll
            for (int mi = 0; mi < 4; mi++)
#pragma unroll
                for (int ni = 0; ni < 4; ni++)
                    acc[mi][ni] = __builtin_amdgcn_mfma_f32_16x16x32_bf16(
                        af[mi], bfg[ni], acc[mi][ni], 0, 0, 0);
        }
        __syncthreads();  // protect LDS before next stage
    }

    // epilogue: C/D layout col=lane&15, row=(lane>>4)*4+reg  (m89/m91-verified)
    int col0 = n0 + wn + fr;
    int rbase = m0 + wm + kq * 4;
    if (OUT_BF16) {
        unsigned short* Cb = (unsigned short*)C + (size_t)blockIdx.z * sCb;
#pragma unroll
        for (int mi = 0; mi < 4; mi++)
#pragma unroll
            for (int ni = 0; ni < 4; ni++)
#pragma unroll
                for (int r = 0; r < 4; r++)
                    Cb[(size_t)(rbase + mi * 16 + r) * ldc + col0 + ni * 16] =
                        f2bf(acc[mi][ni][r] * scale);
    } else {
        float* Cb = (float*)C + (size_t)blockIdx.z * sCb;
#pragma unroll
        for (int mi = 0; mi < 4; mi++)
#pragma unroll
            for (int ni = 0; ni < 4; ni++)
#pragma unroll
                for (int r = 0; r < 4; r++)
                    Cb[(size_t)(rbase + mi * 16 + r) * ldc + col0 + ni * 16] =
                        acc[mi][ni][r] * scale;
    }
}

// ---- kernel: causal row softmax, in place on bf16 S ---------------------
// One wave per row. Full 2048-elem row lives in registers (32 f32/lane):
// one vectorized read, one vectorized write. Mask j>i by select (skipped
// tiles hold 0xAAAA poison = small finite negative; diagonal-tile upper
// half holds finite garbage — both masked here).

__global__ __launch_bounds__(256) void softmax_causal(unsigned short* __restrict__ S) {
    int wave = threadIdx.x >> 6;
    int lane = threadIdx.x & 63;
    int row = blockIdx.x * 4 + wave;
    int i = row & 2047;  // causal row index within batch
    unsigned short* s = S + (size_t)row * 2048;

    uint4 raw[4];
#pragma unroll
    for (int c = 0; c < 4; c++) raw[c] = ((const uint4*)s)[lane + c * 64];

    const float NEG = -1.0e30f;
    float p[32];
    float m = NEG;
#pragma unroll
    for (int c = 0; c < 4; c++) {
        const unsigned int* u = (const unsigned int*)&raw[c];
#pragma unroll
        for (int w = 0; w < 4; w++) {
            int j = c * 512 + lane * 8 + w * 2;
            float f0 = bf2f_hi(u[w] << 16);
            float f1 = bf2f_hi(u[w] & 0xffff0000u);
            f0 = (j <= i) ? f0 : NEG;
            f1 = (j + 1 <= i) ? f1 : NEG;
            p[c * 8 + w * 2] = f0;
            p[c * 8 + w * 2 + 1] = f1;
            m = fmaxf(m, fmaxf(f0, f1));
        }
    }
#pragma unroll
    for (int o = 32; o > 0; o >>= 1) m = fmaxf(m, __shfl_xor(m, o));

    float sum = 0.f;
#pragma unroll
    for (int t = 0; t < 32; t++) {
        p[t] = __expf(p[t] - m);
        sum += p[t];
    }
#pragma unroll
    for (int o = 32; o > 0; o >>= 1) sum += __shfl_xor(sum, o);
    float inv = 1.0f / sum;

#pragma unroll
    for (int c = 0; c < 4; c++) {
        uint4 out;
        unsigned int* u = (unsigned int*)&out;
#pragma unroll
        for (int w = 0; w < 4; w++) {
            unsigned int lo = f2bf(p[c * 8 + w * 2] * inv);
            unsigned int hi = f2bf(p[c * 8 + w * 2 + 1] * inv);
            u[w] = lo | (hi << 16);
        }
        ((uint4*)s)[lane + c * 64] = out;
    }
}

// ---- launch -------------------------------------------------------------

extern "C" void kernel_launch(void* const* d_in, const int* in_sizes, int n_in,
                              void* d_out, int out_size, void* d_ws,
                              size_t ws_size, hipStream_t stream) {
    const float* x = (const float*)d_in[0];
    const float* Wq = (const float*)d_in[1];
    const float* Wk = (const float*)d_in[2];
    const float* Wv = (const float*)d_in[3];
    // causal_mask (d_in[4]) is always 1 in this problem — hardcoded causal.

    char* ws = (char*)d_ws;
    // layout (bytes):
    //   qkv [8192][3072] bf16 : 0        .. 50331648
    //   S   [4][2048][2048]   : 50331648 .. 83886080
    //   xb  [8192][1024]      : 83886080 .. 100663296   (dead after QKV gemm)
    //   vt  [4][1024][2048]   : 83886080  (aliases xb — written after xb dies)
    //   wT  [3072][1024]      : 100663296 .. 106954752
    unsigned short* qkv = (unsigned short*)(ws);
    unsigned short* S = (unsigned short*)(ws + 50331648);
    unsigned short* xb = (unsigned short*)(ws + 83886080);
    unsigned short* vt = (unsigned short*)(ws + 83886080);
    unsigned short* wT = (unsigned short*)(ws + 100663296);

    // 1. x -> bf16  (8388608 elems, 4/thread)
    cvt_f32_to_bf16<<<8192, 256, 0, stream>>>(x, xb, 8388608 / 4);
    // 2. W -> W^T bf16 (3 matrices)
    transpose_w<<<dim3(32, 32, 3), dim3(32, 8), 0, stream>>>(Wq, Wk, Wv, wT);
    // 3. qkv = xb @ [Wq|Wk|Wv]   (M=8192, N=3072, K=1024)
    gemm_bt<true, false, false><<<dim3(24, 64, 1), 256, 0, stream>>>(
        xb, 1024, 0LL, wT, 1024, 0LL, qkv, 3072, 0LL, 1024, 1.0f);
    // 4. V -> V^T per batch
    transpose_v<<<dim3(64, 32, 4), dim3(32, 8), 0, stream>>>(qkv, vt);
    // 5. S = scale * Q K^T  (per batch; skip tiles above diagonal)
    gemm_bt<true, true, false><<<dim3(16, 16, 4), 256, 0, stream>>>(
        qkv, 3072, 2048LL * 3072, qkv + 1024, 3072, 2048LL * 3072, S, 2048,
        2048LL * 2048, 1024, 0.03125f);
    // 6. causal softmax rows, in place (P in bf16)
    softmax_causal<<<2048, 256, 0, stream>>>(S);
    // 7. O = P @ V  (per batch, K limited to causal extent)
    gemm_bt<false, false, true><<<dim3(8, 16, 4), 256, 0, stream>>>(
        S, 2048, 2048LL * 2048, vt, 2048, 1024LL * 2048, d_out, 1024,
        2048LL * 1024, 2048, 1.0f);
}

// Round 3
// 267.186 us; speedup vs baseline: 1.0707x; 1.0518x over previous
//
#include <hip/hip_runtime.h>
#include <hip/hip_bf16.h>
#include <stdint.h>

#define BM 128
#define BN 128
#define BK 64

typedef __attribute__((ext_vector_type(8))) short bf16x8;
typedef __attribute__((ext_vector_type(4))) float floatx4;

// ---- helpers ------------------------------------------------------------

__device__ __forceinline__ unsigned short f2bf(float f) {
    unsigned int x;
    __builtin_memcpy(&x, &f, 4);
    unsigned int r = (x + 0x7fffu + ((x >> 16) & 1u)) >> 16;  // RNE
    return (unsigned short)r;
}

__device__ __forceinline__ float bf2f_hi(unsigned int u_hi_masked) {
    float f;
    __builtin_memcpy(&f, &u_hi_masked, 4);
    return f;
}

// async global->LDS, 16B per lane.  LDS dest must be wave-uniform base + lane*16.
__device__ __forceinline__ void async_copy16(const void* g, void* l) {
    __builtin_amdgcn_global_load_lds(
        (const __attribute__((address_space(1))) void*)(uintptr_t)g,
        (__attribute__((address_space(3))) void*)(uint32_t)(uintptr_t)l,
        16, 0, 0);
}

// ---- kernel 1: fp32 -> bf16 convert (x) ---------------------------------

__global__ void cvt_f32_to_bf16(const float* __restrict__ in,
                                unsigned short* __restrict__ out, int n4) {
    int i = blockIdx.x * 256 + threadIdx.x;
    if (i >= n4) return;
    float4 v = ((const float4*)in)[i];
    ushort4 o;
    o.x = f2bf(v.x);
    o.y = f2bf(v.y);
    o.z = f2bf(v.z);
    o.w = f2bf(v.w);
    ((ushort4*)out)[i] = o;
}

// ---- kernel 2: W [1024,1024] fp32 -> W^T bf16, 3 matrices ---------------

__global__ void transpose_w(const float* __restrict__ Wq,
                            const float* __restrict__ Wk,
                            const float* __restrict__ Wv,
                            unsigned short* __restrict__ wT) {
    __shared__ float tile[32][33];
    const float* W = blockIdx.z == 0 ? Wq : (blockIdx.z == 1 ? Wk : Wv);
    int bx = blockIdx.x * 32;  // input col (n)
    int by = blockIdx.y * 32;  // input row (k)
    int tx = threadIdx.x, ty = threadIdx.y;  // 32x8
    for (int r = 0; r < 32; r += 8)
        tile[ty + r][tx] = W[(size_t)(by + ty + r) * 1024 + bx + tx];
    __syncthreads();
    unsigned short* o = wT + (size_t)blockIdx.z * 1024 * 1024;
    for (int r = 0; r < 32; r += 8)
        o[(size_t)(bx + ty + r) * 1024 + by + tx] = f2bf(tile[tx][ty + r]);
}

// ---- the GEMM: C[m][n] = scale * sum_k A[m][k] * Bt[n][k] ---------------
// m97-style: 128x128 tile, BK=64, 4 waves (2x2), 32 16x16x32 bf16 MFMA/wave
// per k-iter, global_load_lds width-16 staging into unpadded row-major LDS
// [row][64] (layout = lane order, a hard requirement).
// launch_bounds(256,4): 4 blocks/CU (VGPR 76<=128, LDS 32KB*4<=160KB) — the
// structure is barrier/latency-bound, so resident-block overlap is the
// latency-hiding mechanism; 2 blocks/CU was capping it.

template <bool OUT_BF16, bool CAUSAL_SKIP, bool K_LIMIT>
__global__ __launch_bounds__(256, 4) void gemm_bt(
    const unsigned short* __restrict__ A, int lda, long long sAb,
    const unsigned short* __restrict__ B, int ldb, long long sBb,
    void* __restrict__ C, int ldc, long long sCb, int K, float scale) {
    int n0 = blockIdx.x * BN;
    // K_LIMIT (causal PV): reverse m order so longest-K blocks start first.
    int mb = K_LIMIT ? (gridDim.y - 1 - blockIdx.y) : blockIdx.y;
    int m0 = mb * BM;
    if (CAUSAL_SKIP && n0 > m0 + (BM - 1)) return;  // tile fully above diagonal
    int kend = K;
    if (K_LIMIT) {  // causal PV: P[i][j]==0 for j>i, so stop at row-block end
        int lim = m0 + BM;
        kend = lim < K ? lim : K;
    }
    const unsigned short* Ab = A + (size_t)blockIdx.z * sAb;
    const unsigned short* Bb = B + (size_t)blockIdx.z * sBb;

    __shared__ __align__(16) unsigned short As[BM * BK];  // 16 KB
    __shared__ __align__(16) unsigned short Bs[BN * BK];  // 16 KB

    int tid = threadIdx.x;
    int lane = tid & 63;
    int wave = tid >> 6;
    int wm = (wave >> 1) * 64;
    int wn = (wave & 1) * 64;
    int fr = lane & 15;  // fragment row (m) / col (n)
    int kq = lane >> 4;  // k-quad: frag k-chunk base

    floatx4 acc[4][4] = {};

    for (int k0 = 0; k0 < kend; k0 += BK) {
        // staging: chunk c (16B = 8 bf16) covers row c>>3, k-offset (c&7)*8.
        // LDS offset = c*16B (contiguous in lane order: global_load_lds req).
#pragma unroll
        for (int q = 0; q < 4; q++) {
            int c = tid + q * 256;
            int r = c >> 3, ko = (c & 7) * 8;
            async_copy16(Ab + (size_t)(m0 + r) * lda + k0 + ko, &As[c * 8]);
            async_copy16(Bb + (size_t)(n0 + r) * ldb + k0 + ko, &Bs[c * 8]);
        }
        __syncthreads();  // drains vmcnt before LDS reads

#pragma unroll
        for (int kh = 0; kh < 2; kh++) {
            int kc = kh * 4 + kq;
            bf16x8 af[4], bfg[4];
#pragma unroll
            for (int mi = 0; mi < 4; mi++)
                af[mi] = *(const bf16x8*)&As[(wm + mi * 16 + fr) * BK + kc * 8];
#pragma unroll
            for (int ni = 0; ni < 4; ni++)
                bfg[ni] = *(const bf16x8*)&Bs[(wn + ni * 16 + fr) * BK + kc * 8];
#pragma unroll
            for (int mi = 0; mi < 4; mi++)
#pragma unroll
                for (int ni = 0; ni < 4; ni++)
                    acc[mi][ni] = __builtin_amdgcn_mfma_f32_16x16x32_bf16(
                        af[mi], bfg[ni], acc[mi][ni], 0, 0, 0);
        }
        __syncthreads();  // protect LDS before next stage
    }

    // epilogue: C/D layout col=lane&15, row=(lane>>4)*4+reg  (m89/m91-verified)
    int col0 = n0 + wn + fr;
    int rbase = m0 + wm + kq * 4;
    if (OUT_BF16) {
        unsigned short* Cb = (unsigned short*)C + (size_t)blockIdx.z * sCb;
#pragma unroll
        for (int mi = 0; mi < 4; mi++)
#pragma unroll
            for (int ni = 0; ni < 4; ni++)
#pragma unroll
                for (int r = 0; r < 4; r++)
                    Cb[(size_t)(rbase + mi * 16 + r) * ldc + col0 + ni * 16] =
                        f2bf(acc[mi][ni][r] * scale);
    } else {
        float* Cb = (float*)C + (size_t)blockIdx.z * sCb;
#pragma unroll
        for (int mi = 0; mi < 4; mi++)
#pragma unroll
            for (int ni = 0; ni < 4; ni++)
#pragma unroll
                for (int r = 0; r < 4; r++)
                    Cb[(size_t)(rbase + mi * 16 + r) * ldc + col0 + ni * 16] =
                        acc[mi][ni][r] * scale;
    }
}

// ---- kernel: causal row softmax, in place on bf16 S ---------------------
// One wave per row, full row in registers (32 f32/lane), one read + one
// write, shuffle reductions. Mask j>i by select.

__global__ __launch_bounds__(256) void softmax_causal(unsigned short* __restrict__ S) {
    int wave = threadIdx.x >> 6;
    int lane = threadIdx.x & 63;
    int row = blockIdx.x * 4 + wave;
    int i = row & 2047;  // causal row index within batch
    unsigned short* s = S + (size_t)row * 2048;

    uint4 raw[4];
#pragma unroll
    for (int c = 0; c < 4; c++) raw[c] = ((const uint4*)s)[lane + c * 64];

    const float NEG = -1.0e30f;
    float p[32];
    float m = NEG;
#pragma unroll
    for (int c = 0; c < 4; c++) {
        const unsigned int* u = (const unsigned int*)&raw[c];
#pragma unroll
        for (int w = 0; w < 4; w++) {
            int j = c * 512 + lane * 8 + w * 2;
            float f0 = bf2f_hi(u[w] << 16);
            float f1 = bf2f_hi(u[w] & 0xffff0000u);
            f0 = (j <= i) ? f0 : NEG;
            f1 = (j + 1 <= i) ? f1 : NEG;
            p[c * 8 + w * 2] = f0;
            p[c * 8 + w * 2 + 1] = f1;
            m = fmaxf(m, fmaxf(f0, f1));
        }
    }
#pragma unroll
    for (int o = 32; o > 0; o >>= 1) m = fmaxf(m, __shfl_xor(m, o));

    float sum = 0.f;
#pragma unroll
    for (int t = 0; t < 32; t++) {
        p[t] = __expf(p[t] - m);
        sum += p[t];
    }
#pragma unroll
    for (int o = 32; o > 0; o >>= 1) sum += __shfl_xor(sum, o);
    float inv = 1.0f / sum;

#pragma unroll
    for (int c = 0; c < 4; c++) {
        uint4 out;
        unsigned int* u = (unsigned int*)&out;
#pragma unroll
        for (int w = 0; w < 4; w++) {
            unsigned int lo = f2bf(p[c * 8 + w * 2] * inv);
            unsigned int hi = f2bf(p[c * 8 + w * 2 + 1] * inv);
            u[w] = lo | (hi << 16);
        }
        ((uint4*)s)[lane + c * 64] = out;
    }
}

// ---- launch -------------------------------------------------------------

extern "C" void kernel_launch(void* const* d_in, const int* in_sizes, int n_in,
                              void* d_out, int out_size, void* d_ws,
                              size_t ws_size, hipStream_t stream) {
    const float* x = (const float*)d_in[0];
    const float* Wq = (const float*)d_in[1];
    const float* Wk = (const float*)d_in[2];
    const float* Wv = (const float*)d_in[3];
    // causal_mask (d_in[4]) is always 1 in this problem — hardcoded causal.

    char* ws = (char*)d_ws;
    // layout (bytes):
    //   qk [8192][2048] bf16  : 0        .. 33554432   (Q cols 0..1023, K cols 1024..2047)
    //   S  [4][2048][2048]    : 33554432 .. 67108864
    //   vt [1024][8192] bf16  : 67108864 .. 83886080   (V^T, batches side-by-side cols)
    //   xb [8192][1024] bf16  : 83886080 .. 100663296
    //   wT [3][1024][1024]    : 100663296.. 106954752
    unsigned short* qk = (unsigned short*)(ws);
    unsigned short* S = (unsigned short*)(ws + 33554432);
    unsigned short* vt = (unsigned short*)(ws + 67108864);
    unsigned short* xb = (unsigned short*)(ws + 83886080);
    unsigned short* wT = (unsigned short*)(ws + 100663296);

    // 1. x -> bf16  (8388608 elems, 4/thread)
    cvt_f32_to_bf16<<<8192, 256, 0, stream>>>(x, xb, 8388608 / 4);
    // 2. W -> W^T bf16 (3 matrices)
    transpose_w<<<dim3(32, 32, 3), dim3(32, 8), 0, stream>>>(Wq, Wk, Wv, wT);
    // 3. qk = xb @ [Wq|Wk]   (M=8192, N=2048, K=1024)
    gemm_bt<true, false, false><<<dim3(16, 64, 1), 256, 0, stream>>>(
        xb, 1024, 0LL, wT, 1024, 0LL, qk, 2048, 0LL, 1024, 1.0f);
    // 4. vt = WvT @ xb^T: vt[d][bj] = sum_k WvT[d][k] xb[bj][k]
    //    (M=1024 rows of WvT, N=8192 rows of xb, K=1024) — V^T with no
    //    separate transpose pass.
    gemm_bt<true, false, false><<<dim3(64, 8, 1), 256, 0, stream>>>(
        wT + 2 * 1024 * 1024, 1024, 0LL, xb, 1024, 0LL, vt, 8192, 0LL, 1024,
        1.0f);
    // 5. S = scale * Q K^T  (per batch; skip tiles above diagonal)
    gemm_bt<true, true, false><<<dim3(16, 16, 4), 256, 0, stream>>>(
        qk, 2048, 2048LL * 2048, qk + 1024, 2048, 2048LL * 2048, S, 2048,
        2048LL * 2048, 1024, 0.03125f);
    // 6. causal softmax rows, in place (P in bf16)
    softmax_causal<<<2048, 256, 0, stream>>>(S);
    // 7. O = P @ V  (per batch, K limited to causal extent, vt batch = col
    //    offset b*2048 in the [1024][8192] V^T)
    gemm_bt<false, false, true><<<dim3(8, 16, 4), 256, 0, stream>>>(
        S, 2048, 2048LL * 2048, vt, 8192, 2048LL, d_out, 1024,
        2048LL * 1024, 2048, 1.0f);
}

// Round 4
// 260.779 us; speedup vs baseline: 1.0970x; 1.0246x over previous
//
#include <hip/hip_runtime.h>
#include <hip/hip_bf16.h>
#include <stdint.h>

#define BM 128
#define BN 128
#define BK 64

typedef __attribute__((ext_vector_type(8))) short bf16x8;
typedef __attribute__((ext_vector_type(4))) float floatx4;

// ---- helpers ------------------------------------------------------------

__device__ __forceinline__ unsigned short f2bf(float f) {
    unsigned int x;
    __builtin_memcpy(&x, &f, 4);
    unsigned int r = (x + 0x7fffu + ((x >> 16) & 1u)) >> 16;  // RNE
    return (unsigned short)r;
}

__device__ __forceinline__ float bf2f_hi(unsigned int u_hi_masked) {
    float f;
    __builtin_memcpy(&f, &u_hi_masked, 4);
    return f;
}

// async global->LDS, 16B per lane.  LDS dest must be wave-uniform base + lane*16.
__device__ __forceinline__ void async_copy16(const void* g, void* l) {
    __builtin_amdgcn_global_load_lds(
        (const __attribute__((address_space(1))) void*)(uintptr_t)g,
        (__attribute__((address_space(3))) void*)(uint32_t)(uintptr_t)l,
        16, 0, 0);
}

// ---- prep: fp32->bf16 convert of x  +  W^T bf16 of Wq/Wk/Wv -------------
// Merged into one dispatch (block-uniform branch) to cut a launch gap.

__global__ __launch_bounds__(256) void prep(const float* __restrict__ x,
                                            const float* __restrict__ Wq,
                                            const float* __restrict__ Wk,
                                            const float* __restrict__ Wv,
                                            unsigned short* __restrict__ xb,
                                            unsigned short* __restrict__ wT) {
    __shared__ float tile[32][33];
    int bid = blockIdx.x;
    int tid = threadIdx.x;
    if (bid < 8192) {  // cvt: 8192 blocks x 256 threads x float4
        int i = bid * 256 + tid;
        float4 v = ((const float4*)x)[i];
        ushort4 o;
        o.x = f2bf(v.x);
        o.y = f2bf(v.y);
        o.z = f2bf(v.z);
        o.w = f2bf(v.w);
        ((ushort4*)xb)[i] = o;
    } else {  // transpose W: 3 x 1024 blocks, 32x32 tiles
        int w = bid - 8192;
        int z = w >> 10;
        int r = w & 1023;
        int bx = (r & 31) * 32;  // input col (n)
        int by = (r >> 5) * 32;  // input row (k)
        const float* W = z == 0 ? Wq : (z == 1 ? Wk : Wv);
        int tx = tid & 31, ty = tid >> 5;  // 32x8
        for (int rr = 0; rr < 32; rr += 8)
            tile[ty + rr][tx] = W[(size_t)(by + ty + rr) * 1024 + bx + tx];
        __syncthreads();
        unsigned short* o = wT + (size_t)z * 1024 * 1024;
        for (int rr = 0; rr < 32; rr += 8)
            o[(size_t)(bx + ty + rr) * 1024 + by + tx] = f2bf(tile[tx][ty + rr]);
    }
}

// ---- GEMM core: C[m][n] = scale * sum_k A[m][k] * Bt[n][k] --------------
// m97-style: 128x128 tile, BK=64, 4 waves (2x2), 32 16x16x32 bf16 MFMA/wave
// per k-iter, global_load_lds width-16 staging into unpadded row-major LDS
// [row][64] (layout = lane order, a hard requirement).  Runtime flags are
// block-uniform (no divergence cost).

__device__ __forceinline__ void gemm_core(const unsigned short* __restrict__ A,
                                          int lda,
                                          const unsigned short* __restrict__ B,
                                          int ldb, void* __restrict__ C,
                                          int ldc, bool out_bf16, int kend,
                                          float scale, int m0, int n0) {
    __shared__ __align__(16) unsigned short As[BM * BK];  // 16 KB
    __shared__ __align__(16) unsigned short Bs[BN * BK];  // 16 KB

    int tid = threadIdx.x;
    int lane = tid & 63;
    int wave = tid >> 6;
    int wm = (wave >> 1) * 64;
    int wn = (wave & 1) * 64;
    int fr = lane & 15;  // fragment row (m) / col (n)
    int kq = lane >> 4;  // k-quad

    floatx4 acc[4][4] = {};

    for (int k0 = 0; k0 < kend; k0 += BK) {
        // staging: chunk c (16B = 8 bf16) covers row c>>3, k-offset (c&7)*8.
        // LDS offset = c*16B (contiguous in lane order: global_load_lds req).
#pragma unroll
        for (int q = 0; q < 4; q++) {
            int c = tid + q * 256;
            int r = c >> 3, ko = (c & 7) * 8;
            async_copy16(A + (size_t)(m0 + r) * lda + k0 + ko, &As[c * 8]);
            async_copy16(B + (size_t)(n0 + r) * ldb + k0 + ko, &Bs[c * 8]);
        }
        __syncthreads();  // drains vmcnt before LDS reads

#pragma unroll
        for (int kh = 0; kh < 2; kh++) {
            int kc = kh * 4 + kq;
            bf16x8 af[4], bfg[4];
#pragma unroll
            for (int mi = 0; mi < 4; mi++)
                af[mi] = *(const bf16x8*)&As[(wm + mi * 16 + fr) * BK + kc * 8];
#pragma unroll
            for (int ni = 0; ni < 4; ni++)
                bfg[ni] = *(const bf16x8*)&Bs[(wn + ni * 16 + fr) * BK + kc * 8];
#pragma unroll
            for (int mi = 0; mi < 4; mi++)
#pragma unroll
                for (int ni = 0; ni < 4; ni++)
                    acc[mi][ni] = __builtin_amdgcn_mfma_f32_16x16x32_bf16(
                        af[mi], bfg[ni], acc[mi][ni], 0, 0, 0);
        }
        __syncthreads();  // protect LDS before next stage
    }

    // epilogue: C/D layout col=lane&15, row=(lane>>4)*4+reg  (m89/m91-verified)
    int col0 = n0 + wn + fr;
    int rbase = m0 + wm + kq * 4;
    if (out_bf16) {
        unsigned short* Cb = (unsigned short*)C;
#pragma unroll
        for (int mi = 0; mi < 4; mi++)
#pragma unroll
            for (int ni = 0; ni < 4; ni++)
#pragma unroll
                for (int r = 0; r < 4; r++)
                    Cb[(size_t)(rbase + mi * 16 + r) * ldc + col0 + ni * 16] =
                        f2bf(acc[mi][ni][r] * scale);
    } else {
        float* Cb = (float*)C;
#pragma unroll
        for (int mi = 0; mi < 4; mi++)
#pragma unroll
            for (int ni = 0; ni < 4; ni++)
#pragma unroll
                for (int r = 0; r < 4; r++)
                    Cb[(size_t)(rbase + mi * 16 + r) * ldc + col0 + ni * 16] =
                        acc[mi][ni][r] * scale;
    }
}

// ---- stage B: qk = xb @ [Wq|Wk]  (M=8192, N=2048, K=1024) ---------------

__global__ __launch_bounds__(256, 4) void gemm_qk(
    const unsigned short* __restrict__ xb, const unsigned short* __restrict__ wT,
    unsigned short* __restrict__ qk) {
    gemm_core(xb, 1024, wT, 1024, qk, 2048, true, 1024, 1.0f,
              blockIdx.y * BM, blockIdx.x * BN);
}

// ---- stage C: S = scale*Q K^T (causal-skip) MERGED WITH vt = WvT @ xb^T --
// Independent GEMMs in one dispatch: the ~480 causal-skip blocks exit
// instantly and vt blocks fill those CUs (tail overlap).

__global__ __launch_bounds__(256, 4) void gemm_s_vt(
    const unsigned short* __restrict__ qk, const unsigned short* __restrict__ wTv,
    const unsigned short* __restrict__ xb, unsigned short* __restrict__ S,
    unsigned short* __restrict__ vt) {
    int bid = blockIdx.x;
    if (bid < 1024) {  // S: 4 batches x 16x16 blocks
        int bz = bid >> 8;
        int r = bid & 255;
        int m0 = (r >> 4) * BM;
        int n0 = (r & 15) * BN;
        if (n0 > m0 + (BM - 1)) return;  // tile fully above diagonal
        const unsigned short* Q = qk + (size_t)bz * 2048 * 2048;
        const unsigned short* K = qk + (size_t)bz * 2048 * 2048 + 1024;
        unsigned short* Sb = S + (size_t)bz * 2048 * 2048;
        gemm_core(Q, 2048, K, 2048, Sb, 2048, true, 1024, 0.03125f, m0, n0);
    } else {  // vt: 8 m-blocks x 64 n-blocks  (M=1024 WvT rows, N=8192 xb rows)
        int r = bid - 1024;
        int m0 = (r >> 6) * BM;
        int n0 = (r & 63) * BN;
        gemm_core(wTv, 1024, xb, 1024, vt, 8192, true, 1024, 1.0f, m0, n0);
    }
}

// ---- stage E: O = P @ V  (per batch, K limited to causal extent) --------

__global__ __launch_bounds__(256, 4) void gemm_pv(
    const unsigned short* __restrict__ S, const unsigned short* __restrict__ vt,
    float* __restrict__ out) {
    int bz = blockIdx.z;
    int mb = gridDim.y - 1 - blockIdx.y;  // longest-K blocks first
    int m0 = mb * BM;
    int kend = m0 + BM < 2048 ? m0 + BM : 2048;  // P[i][j]==0 for j>i
    gemm_core(S + (size_t)bz * 2048 * 2048, 2048, vt + (size_t)bz * 2048, 8192,
              out + (size_t)bz * 2048 * 1024, 1024, false, kend, 1.0f, m0,
              blockIdx.x * BN);
}

// ---- stage D: causal row softmax, in place on bf16 S --------------------
// One wave per row, full row in registers (32 f32/lane), one read + one
// write, shuffle reductions. Mask j>i by select.

__global__ __launch_bounds__(256) void softmax_causal(unsigned short* __restrict__ S) {
    int wave = threadIdx.x >> 6;
    int lane = threadIdx.x & 63;
    int row = blockIdx.x * 4 + wave;
    int i = row & 2047;  // causal row index within batch
    unsigned short* s = S + (size_t)row * 2048;

    uint4 raw[4];
#pragma unroll
    for (int c = 0; c < 4; c++) raw[c] = ((const uint4*)s)[lane + c * 64];

    const float NEG = -1.0e30f;
    float p[32];
    float m = NEG;
#pragma unroll
    for (int c = 0; c < 4; c++) {
        const unsigned int* u = (const unsigned int*)&raw[c];
#pragma unroll
        for (int w = 0; w < 4; w++) {
            int j = c * 512 + lane * 8 + w * 2;
            float f0 = bf2f_hi(u[w] << 16);
            float f1 = bf2f_hi(u[w] & 0xffff0000u);
            f0 = (j <= i) ? f0 : NEG;
            f1 = (j + 1 <= i) ? f1 : NEG;
            p[c * 8 + w * 2] = f0;
            p[c * 8 + w * 2 + 1] = f1;
            m = fmaxf(m, fmaxf(f0, f1));
        }
    }
#pragma unroll
    for (int o = 32; o > 0; o >>= 1) m = fmaxf(m, __shfl_xor(m, o));

    float sum = 0.f;
#pragma unroll
    for (int t = 0; t < 32; t++) {
        p[t] = __expf(p[t] - m);
        sum += p[t];
    }
#pragma unroll
    for (int o = 32; o > 0; o >>= 1) sum += __shfl_xor(sum, o);
    float inv = 1.0f / sum;

#pragma unroll
    for (int c = 0; c < 4; c++) {
        uint4 out;
        unsigned int* u = (unsigned int*)&out;
#pragma unroll
        for (int w = 0; w < 4; w++) {
            unsigned int lo = f2bf(p[c * 8 + w * 2] * inv);
            unsigned int hi = f2bf(p[c * 8 + w * 2 + 1] * inv);
            u[w] = lo | (hi << 16);
        }
        ((uint4*)s)[lane + c * 64] = out;
    }
}

// ---- launch -------------------------------------------------------------

extern "C" void kernel_launch(void* const* d_in, const int* in_sizes, int n_in,
                              void* d_out, int out_size, void* d_ws,
                              size_t ws_size, hipStream_t stream) {
    const float* x = (const float*)d_in[0];
    const float* Wq = (const float*)d_in[1];
    const float* Wk = (const float*)d_in[2];
    const float* Wv = (const float*)d_in[3];
    // causal_mask (d_in[4]) is always 1 in this problem — hardcoded causal.

    char* ws = (char*)d_ws;
    // layout (bytes):
    //   qk [8192][2048] bf16  : 0        .. 33554432   (Q cols 0..1023, K cols 1024..2047)
    //   S  [4][2048][2048]    : 33554432 .. 67108864
    //   vt [1024][8192] bf16  : 67108864 .. 83886080   (V^T, batches side-by-side cols)
    //   xb [8192][1024] bf16  : 83886080 .. 100663296
    //   wT [3][1024][1024]    : 100663296.. 106954752
    unsigned short* qk = (unsigned short*)(ws);
    unsigned short* S = (unsigned short*)(ws + 33554432);
    unsigned short* vt = (unsigned short*)(ws + 67108864);
    unsigned short* xb = (unsigned short*)(ws + 83886080);
    unsigned short* wT = (unsigned short*)(ws + 100663296);

    // A. x->bf16 (8192 blocks) + W->W^T bf16 (3072 blocks), one dispatch
    prep<<<11264, 256, 0, stream>>>(x, Wq, Wk, Wv, xb, wT);
    // B. qk = xb @ [Wq|Wk]   (M=8192, N=2048, K=1024)
    gemm_qk<<<dim3(16, 64), 256, 0, stream>>>(xb, wT, qk);
    // C. S = scale * Q K^T (causal-skip)  +  vt = WvT @ xb^T, one dispatch
    gemm_s_vt<<<1536, 256, 0, stream>>>(qk, wT + 2 * 1024 * 1024, xb, S, vt);
    // D. causal softmax rows, in place (P in bf16)
    softmax_causal<<<2048, 256, 0, stream>>>(S);
    // E. O = P @ V  (per batch, K limited to causal extent)
    gemm_pv<<<dim3(8, 16, 4), 256, 0, stream>>>(S, vt, (float*)d_out);
}

// Round 5
// 255.278 us; speedup vs baseline: 1.1207x; 1.0215x over previous
//
#include <hip/hip_runtime.h>
#include <hip/hip_bf16.h>
#include <stdint.h>

#define BM 128
#define BN 128
#define BK 64

typedef __attribute__((ext_vector_type(8))) short bf16x8;
typedef __attribute__((ext_vector_type(4))) float floatx4;

// ---- helpers ------------------------------------------------------------

__device__ __forceinline__ unsigned short f2bf(float f) {
    unsigned int x;
    __builtin_memcpy(&x, &f, 4);
    unsigned int r = (x + 0x7fffu + ((x >> 16) & 1u)) >> 16;  // RNE
    return (unsigned short)r;
}

__device__ __forceinline__ float bf2f_hi(unsigned int u_hi_masked) {
    float f;
    __builtin_memcpy(&f, &u_hi_masked, 4);
    return f;
}

// async global->LDS, 16B per lane.  LDS dest must be wave-uniform base + lane*16.
__device__ __forceinline__ void async_copy16(const void* g, void* l) {
    __builtin_amdgcn_global_load_lds(
        (const __attribute__((address_space(1))) void*)(uintptr_t)g,
        (__attribute__((address_space(3))) void*)(uint32_t)(uintptr_t)l,
        16, 0, 0);
}

// ---- prep: fp32->bf16 convert of x  +  W^T bf16 of Wq/Wk/Wv -------------

__global__ __launch_bounds__(256) void prep(const float* __restrict__ x,
                                            const float* __restrict__ Wq,
                                            const float* __restrict__ Wk,
                                            const float* __restrict__ Wv,
                                            unsigned short* __restrict__ xb,
                                            unsigned short* __restrict__ wT) {
    __shared__ float tile[32][33];
    int bid = blockIdx.x;
    int tid = threadIdx.x;
    if (bid < 8192) {  // cvt: 8192 blocks x 256 threads x float4
        int i = bid * 256 + tid;
        float4 v = ((const float4*)x)[i];
        ushort4 o;
        o.x = f2bf(v.x);
        o.y = f2bf(v.y);
        o.z = f2bf(v.z);
        o.w = f2bf(v.w);
        ((ushort4*)xb)[i] = o;
    } else {  // transpose W: 3 x 1024 blocks, 32x32 tiles
        int w = bid - 8192;
        int z = w >> 10;
        int r = w & 1023;
        int bx = (r & 31) * 32;  // input col (n)
        int by = (r >> 5) * 32;  // input row (k)
        const float* W = z == 0 ? Wq : (z == 1 ? Wk : Wv);
        int tx = tid & 31, ty = tid >> 5;  // 32x8
        for (int rr = 0; rr < 32; rr += 8)
            tile[ty + rr][tx] = W[(size_t)(by + ty + rr) * 1024 + bx + tx];
        __syncthreads();
        unsigned short* o = wT + (size_t)z * 1024 * 1024;
        for (int rr = 0; rr < 32; rr += 8)
            o[(size_t)(bx + ty + rr) * 1024 + by + tx] = f2bf(tile[tx][ty + rr]);
    }
}

// ---- GEMM core: C[m][n] = scale * sum_k A[m][k] * Bt[n][k] --------------
// m97-style: 128x128 tile, BK=64, 4 waves (2x2), 32 16x16x32 bf16 MFMA/wave
// per k-iter, global_load_lds width-16 staging into unpadded row-major LDS
// [row][64] (layout = lane order, a hard requirement).

__device__ __forceinline__ void gemm_core(const unsigned short* __restrict__ A,
                                          int lda,
                                          const unsigned short* __restrict__ B,
                                          int ldb, void* __restrict__ C,
                                          int ldc, bool out_bf16, int kend,
                                          float scale, int m0, int n0) {
    __shared__ __align__(16) unsigned short As[BM * BK];  // 16 KB
    __shared__ __align__(16) unsigned short Bs[BN * BK];  // 16 KB

    int tid = threadIdx.x;
    int lane = tid & 63;
    int wave = tid >> 6;
    int wm = (wave >> 1) * 64;
    int wn = (wave & 1) * 64;
    int fr = lane & 15;  // fragment row (m) / col (n)
    int kq = lane >> 4;  // k-quad

    floatx4 acc[4][4] = {};

    for (int k0 = 0; k0 < kend; k0 += BK) {
#pragma unroll
        for (int q = 0; q < 4; q++) {
            int c = tid + q * 256;
            int r = c >> 3, ko = (c & 7) * 8;
            async_copy16(A + (size_t)(m0 + r) * lda + k0 + ko, &As[c * 8]);
            async_copy16(B + (size_t)(n0 + r) * ldb + k0 + ko, &Bs[c * 8]);
        }
        __syncthreads();  // drains vmcnt before LDS reads

#pragma unroll
        for (int kh = 0; kh < 2; kh++) {
            int kc = kh * 4 + kq;
            bf16x8 af[4], bfg[4];
#pragma unroll
            for (int mi = 0; mi < 4; mi++)
                af[mi] = *(const bf16x8*)&As[(wm + mi * 16 + fr) * BK + kc * 8];
#pragma unroll
            for (int ni = 0; ni < 4; ni++)
                bfg[ni] = *(const bf16x8*)&Bs[(wn + ni * 16 + fr) * BK + kc * 8];
#pragma unroll
            for (int mi = 0; mi < 4; mi++)
#pragma unroll
                for (int ni = 0; ni < 4; ni++)
                    acc[mi][ni] = __builtin_amdgcn_mfma_f32_16x16x32_bf16(
                        af[mi], bfg[ni], acc[mi][ni], 0, 0, 0);
        }
        __syncthreads();  // protect LDS before next stage
    }

    // epilogue: C/D layout col=lane&15, row=(lane>>4)*4+reg  (m89/m91-verified)
    int col0 = n0 + wn + fr;
    int rbase = m0 + wm + kq * 4;
    if (out_bf16) {
        unsigned short* Cb = (unsigned short*)C;
#pragma unroll
        for (int mi = 0; mi < 4; mi++)
#pragma unroll
            for (int ni = 0; ni < 4; ni++)
#pragma unroll
                for (int r = 0; r < 4; r++)
                    Cb[(size_t)(rbase + mi * 16 + r) * ldc + col0 + ni * 16] =
                        f2bf(acc[mi][ni][r] * scale);
    } else {
        float* Cb = (float*)C;
#pragma unroll
        for (int mi = 0; mi < 4; mi++)
#pragma unroll
            for (int ni = 0; ni < 4; ni++)
#pragma unroll
                for (int r = 0; r < 4; r++)
                    Cb[(size_t)(rbase + mi * 16 + r) * ldc + col0 + ni * 16] =
                        acc[mi][ni][r] * scale;
    }
}

// ---- stage B: qk = xb @ [Wq|Wk]  (M=8192, N=2048, K=1024) ---------------
// Exactly 1024 blocks = one full 4-blocks/CU residency round.

__global__ __launch_bounds__(256, 4) void gemm_qk(
    const unsigned short* __restrict__ xb, const unsigned short* __restrict__ wT,
    unsigned short* __restrict__ qk) {
    gemm_core(xb, 1024, wT, 1024, qk, 2048, true, 1024, 1.0f,
              blockIdx.y * BM, blockIdx.x * BN);
}

// ---- stage C: S = scale * Q K^T, lower-triangle blocks only -------------
// 544 blocks (4 batches x 136 tri-tiles) — all-resident, no skip blocks.

__global__ __launch_bounds__(256, 4) void gemm_s(
    const unsigned short* __restrict__ qk, unsigned short* __restrict__ S) {
    int bid = blockIdx.x;
    int bz = bid / 136;
    int r = bid - bz * 136;
    // triangular index: mb = row, nb = col <= mb  (mb*(mb+1)/2 + nb == r)
    int mb = (int)((sqrtf(8.0f * r + 1.0f) - 1.0f) * 0.5f);
    while ((mb + 1) * (mb + 2) / 2 <= r) mb++;
    while (mb * (mb + 1) / 2 > r) mb--;
    int nb = r - mb * (mb + 1) / 2;
    const unsigned short* Q = qk + (size_t)bz * 2048 * 2048;
    const unsigned short* K = Q + 1024;
    unsigned short* Sb = S + (size_t)bz * 2048 * 2048;
    gemm_core(Q, 2048, K, 2048, Sb, 2048, true, 1024, 0.03125f, mb * BM,
              nb * BN);
}

// ---- stage D: softmax (causal, in place)  MERGED WITH  vt = WvT @ xb^T --
// vt is independent of S; softmax underutilizes the machine (light blocks).
// GEMM blocks first so they start earliest.

__global__ __launch_bounds__(256, 4) void sm_vt(
    unsigned short* __restrict__ S, const unsigned short* __restrict__ wTv,
    const unsigned short* __restrict__ xb, unsigned short* __restrict__ vt) {
    int bid = blockIdx.x;
    if (bid < 512) {  // vt: 8 m-blocks x 64 n-blocks (M=1024 WvT, N=8192 xb)
        gemm_core(wTv, 1024, xb, 1024, vt, 8192, true, 1024, 1.0f,
                  (bid >> 6) * BM, (bid & 63) * BN);
        return;
    }
    // softmax: one wave per row, full row in registers (32 f32/lane)
    int wave = threadIdx.x >> 6;
    int lane = threadIdx.x & 63;
    int row = (bid - 512) * 4 + wave;
    int i = row & 2047;  // causal row index within batch
    unsigned short* s = S + (size_t)row * 2048;

    uint4 raw[4];
#pragma unroll
    for (int c = 0; c < 4; c++) raw[c] = ((const uint4*)s)[lane + c * 64];

    const float NEG = -1.0e30f;
    float p[32];
    float m = NEG;
#pragma unroll
    for (int c = 0; c < 4; c++) {
        const unsigned int* u = (const unsigned int*)&raw[c];
#pragma unroll
        for (int w = 0; w < 4; w++) {
            int j = c * 512 + lane * 8 + w * 2;
            float f0 = bf2f_hi(u[w] << 16);
            float f1 = bf2f_hi(u[w] & 0xffff0000u);
            f0 = (j <= i) ? f0 : NEG;
            f1 = (j + 1 <= i) ? f1 : NEG;
            p[c * 8 + w * 2] = f0;
            p[c * 8 + w * 2 + 1] = f1;
            m = fmaxf(m, fmaxf(f0, f1));
        }
    }
#pragma unroll
    for (int o = 32; o > 0; o >>= 1) m = fmaxf(m, __shfl_xor(m, o));

    float sum = 0.f;
#pragma unroll
    for (int t = 0; t < 32; t++) {
        p[t] = __expf(p[t] - m);
        sum += p[t];
    }
#pragma unroll
    for (int o = 32; o > 0; o >>= 1) sum += __shfl_xor(sum, o);
    float inv = 1.0f / sum;

#pragma unroll
    for (int c = 0; c < 4; c++) {
        uint4 out;
        unsigned int* u = (unsigned int*)&out;
#pragma unroll
        for (int w = 0; w < 4; w++) {
            unsigned int lo = f2bf(p[c * 8 + w * 2] * inv);
            unsigned int hi = f2bf(p[c * 8 + w * 2 + 1] * inv);
            u[w] = lo | (hi << 16);
        }
        ((uint4*)s)[lane + c * 64] = out;
    }
}

// ---- stage E: O = P @ V  (per batch, K limited to causal extent) --------

__global__ __launch_bounds__(256, 4) void gemm_pv(
    const unsigned short* __restrict__ S, const unsigned short* __restrict__ vt,
    float* __restrict__ out) {
    int bz = blockIdx.z;
    int mb = gridDim.y - 1 - blockIdx.y;  // longest-K blocks first
    int m0 = mb * BM;
    int kend = m0 + BM < 2048 ? m0 + BM : 2048;  // P[i][j]==0 for j>i
    gemm_core(S + (size_t)bz * 2048 * 2048, 2048, vt + (size_t)bz * 2048, 8192,
              out + (size_t)bz * 2048 * 1024, 1024, false, kend, 1.0f, m0,
              blockIdx.x * BN);
}

// ---- launch -------------------------------------------------------------

extern "C" void kernel_launch(void* const* d_in, const int* in_sizes, int n_in,
                              void* d_out, int out_size, void* d_ws,
                              size_t ws_size, hipStream_t stream) {
    const float* x = (const float*)d_in[0];
    const float* Wq = (const float*)d_in[1];
    const float* Wk = (const float*)d_in[2];
    const float* Wv = (const float*)d_in[3];
    // causal_mask (d_in[4]) is always 1 in this problem — hardcoded causal.

    char* ws = (char*)d_ws;
    // layout (bytes):
    //   qk [8192][2048] bf16  : 0        .. 33554432   (Q cols 0..1023, K cols 1024..2047)
    //   S  [4][2048][2048]    : 33554432 .. 67108864
    //   vt [1024][8192] bf16  : 67108864 .. 83886080   (V^T, batches side-by-side cols)
    //   xb [8192][1024] bf16  : 83886080 .. 100663296
    //   wT [3][1024][1024]    : 100663296.. 106954752
    unsigned short* qk = (unsigned short*)(ws);
    unsigned short* S = (unsigned short*)(ws + 33554432);
    unsigned short* vt = (unsigned short*)(ws + 67108864);
    unsigned short* xb = (unsigned short*)(ws + 83886080);
    unsigned short* wT = (unsigned short*)(ws + 100663296);

    // A. x->bf16 (8192 blocks) + W->W^T bf16 (3072 blocks), one dispatch
    prep<<<11264, 256, 0, stream>>>(x, Wq, Wk, Wv, xb, wT);
    // B. qk = xb @ [Wq|Wk]   (M=8192, N=2048, K=1024) — 1024 blocks
    gemm_qk<<<dim3(16, 64), 256, 0, stream>>>(xb, wT, qk);
    // C. S = scale * Q K^T — 544 lower-triangle blocks only
    gemm_s<<<544, 256, 0, stream>>>(qk, S);
    // D. softmax (2048 light blocks) + vt GEMM (512 blocks), one dispatch
    sm_vt<<<2560, 256, 0, stream>>>(S, wT + 2 * 1024 * 1024, xb, vt);
    // E. O = P @ V  (per batch, K limited to causal extent) — 512 blocks
    gemm_pv<<<dim3(8, 16, 4), 256, 0, stream>>>(S, vt, (float*)d_out);
}